// Round 6
// baseline (633.224 us; speedup 1.0000x reference)
//
#include <hip/hip_runtime.h>

#define N_NODES 50000
#define N_EDGES 800000
#define F_INPUT 256
#define HDIM 64
#define NCLS 10
#define NGRAPH 64

#define BSHIFT 7                 // 128 nodes per bucket
#define NBUCK 391                // ceil(50000/128)
#define CAP 2688                 // bucket edge capacity (mean 2048, sigma ~45)

// ---------------- degree histogram ----------------
__global__ __launch_bounds__(256) void k_deg_count(const int* __restrict__ dst,
                                                   int* __restrict__ degi, int E) {
    int e = blockIdx.x * 256 + threadIdx.x;
    if (e < E) atomicAdd(&degi[dst[e]], 1);
}

// ---------------- prefix sum (3-phase) ----------------
__global__ __launch_bounds__(256) void k_scan1(const int* __restrict__ degi,
                                               int* __restrict__ off,
                                               int* __restrict__ bsum, int n) {
    __shared__ int tmp[256];
    int t = threadIdx.x;
    int i = blockIdx.x * 256 + t;
    int v = (i < n) ? degi[i] : 0;
    tmp[t] = v;
    __syncthreads();
    for (int d = 1; d < 256; d <<= 1) {
        int x = (t >= d) ? tmp[t - d] : 0;
        __syncthreads();
        tmp[t] += x;
        __syncthreads();
    }
    if (i < n) off[i] = tmp[t] - v;        // exclusive within block
    if (t == 255) bsum[blockIdx.x] = tmp[t];
}

__global__ __launch_bounds__(256) void k_scan2(int* __restrict__ bsum, int nb) {
    __shared__ int tmp[256];
    int t = threadIdx.x;
    int v = (t < nb) ? bsum[t] : 0;
    tmp[t] = v;
    __syncthreads();
    for (int d = 1; d < 256; d <<= 1) {
        int x = (t >= d) ? tmp[t - d] : 0;
        __syncthreads();
        tmp[t] += x;
        __syncthreads();
    }
    if (t < nb) bsum[t] = tmp[t] - v;      // exclusive block bases
}

// scan finalize + GCN norm factors + bucket cursor seed (fused)
__global__ __launch_bounds__(256) void k_scan3(int* __restrict__ off,
                                               int* __restrict__ bcur,
                                               const int* __restrict__ bsum,
                                               const int* __restrict__ degi,
                                               float* __restrict__ dis,
                                               float* __restrict__ selfn, int n) {
    int i = blockIdx.x * 256 + threadIdx.x;
    if (i < n) {
        int o = off[i] + bsum[blockIdx.x];
        off[i] = o;
        if ((i & 127) == 0) bcur[i >> BSHIFT] = o;   // bucket region start
        float d = (float)(degi[i] + 1);
        dis[i] = rsqrtf(d);
        selfn[i] = 1.0f / d;
    }
}

// ---------------- pass A: LDS-staged bucket partition ----------------
__global__ __launch_bounds__(256) void k_part(const int* __restrict__ src,
                                              const int* __restrict__ dst,
                                              int* __restrict__ bcur,
                                              int* __restrict__ stage, int E) {
    __shared__ int cnt[NBUCK];
    __shared__ int base[NBUCK];
    const int tid = threadIdx.x;
    const int e0 = blockIdx.x * 4096;
    int pb[16], pv[16];
    for (int t = tid; t < NBUCK; t += 256) cnt[t] = 0;
    __syncthreads();
#pragma unroll
    for (int j = 0; j < 16; ++j) {
        int e = e0 + j * 256 + tid;
        if (e < E) {
            int s = src[e], d = dst[e];
            pb[j] = d >> BSHIFT;
            pv[j] = (s << BSHIFT) | (d & 127);
            atomicAdd(&cnt[pb[j]], 1);
        } else pb[j] = -1;
    }
    __syncthreads();
    for (int t = tid; t < NBUCK; t += 256) {
        int c = cnt[t];
        base[t] = c ? atomicAdd(&bcur[t], c) : 0;
        cnt[t] = 0;
    }
    __syncthreads();
#pragma unroll
    for (int j = 0; j < 16; ++j) {
        if (pb[j] >= 0) {
            int r = atomicAdd(&cnt[pb[j]], 1);
            stage[base[pb[j]] + r] = pv[j];
        }
    }
}

// ---------------- pass B: per-bucket LDS counting sort -> CSR ----------------
__global__ __launch_bounds__(256) void k_csr(const int* __restrict__ stage,
                                             const int* __restrict__ off,
                                             const float* __restrict__ dis,
                                             int2* __restrict__ eadj, int E, int n) {
    __shared__ int lcur[128];
    __shared__ int2 ebuf[CAP];
    const int b = blockIdx.x;
    const int tid = threadIdx.x;
    const int n0 = b << BSHIFT;
    const int nn = min(128, n - n0);
    const int r0 = off[n0];
    const int r1 = (b == NBUCK - 1) ? E : off[n0 + 128];
    const int len = r1 - r0;
    if (tid < nn) lcur[tid] = off[n0 + tid] - r0;
    __syncthreads();
    const bool fits = (len <= CAP);
    for (int j = r0 + tid; j < r1; j += 256) {
        int p = stage[j];
        int s = p >> BSHIFT;
        int dl = p & 127;
        float w = dis[s] * dis[n0 + dl];
        int rk = atomicAdd(&lcur[dl], 1);
        int2 v = make_int2(s, __float_as_int(w));
        if (fits) ebuf[rk] = v;
        else eadj[r0 + rk] = v;          // statistical-overflow fallback
    }
    __syncthreads();
    if (fits)
        for (int j = tid; j < len; j += 256) eadj[r0 + j] = ebuf[j];
}

// ---------------- fp32 GEMM: C[n,64] = A[n,K] @ B[K,64] ----------------
// 128x64 tile, 256 threads (32x8), 4x8 micro-tile, k-grouped x4 inner loop:
// 12 ds_read_b128 per 128 FMA -> LDS demand 192 B/cyc < 256 peak (FMA-bound).
// A-reads broadcast across tx; XOR column swizzle spreads ty over distinct
// bank quads (conflict-free). NOTE: no pointer arrays / dynamic local indexing
// in the inner loop — round 5's ap[]/bl[] pointer arrays defeated SROA and
// spilled acc to scratch (VGPR 256, FETCH 165MB). Flat arrays + constant
// indices only.
template <int K>
__global__ __launch_bounds__(256) void k_gemm(const float* __restrict__ A,
                                              const float* __restrict__ B,
                                              float* __restrict__ C, int n) {
    __shared__ float As[128][68];
    __shared__ float Bs[64][64];
    const int tid = threadIdx.x;
    const int row0 = blockIdx.x * 128;
    const int tx = tid & 7;          // col group 0..7
    const int ty = tid >> 3;         // row group 0..31
    const int tr = ty * 4;           // 4 rows per thread
    const int tc = tx * 8;           // 8 cols per thread
    const int lk = (tid & 15) * 4;   // staging k offset
    const int lr = tid >> 4;         // staging row 0..15
    const int rswz = ((ty & 7) << 2);   // read swizzle: (row>>2)&7 == ty&7

    float acc[4][8];
#pragma unroll
    for (int i = 0; i < 4; ++i)
#pragma unroll
        for (int j = 0; j < 8; ++j) acc[i][j] = 0.0f;

    for (int kc = 0; kc < K; kc += 64) {
        // stage A: 128 rows x 64 k (swizzled columns)
#pragma unroll
        for (int p = 0; p < 8; ++p) {
            int r = lr + p * 16;
            int grow = row0 + r;
            float4 v = make_float4(0.f, 0.f, 0.f, 0.f);
            if (grow < n) v = *(const float4*)(A + (size_t)grow * K + kc + lk);
            *(float4*)&As[r][lk ^ (((r >> 2) & 7) << 2)] = v;
        }
        // stage B: 64 k x 64 cols
#pragma unroll
        for (int p = 0; p < 4; ++p) {
            int kk = lr + p * 16;
            *(float4*)&Bs[kk][lk] = *(const float4*)(B + (size_t)(kc + kk) * HDIM + lk);
        }
        __syncthreads();
#pragma unroll
        for (int kg = 0; kg < 16; ++kg) {
            const int ac = (kg * 4) ^ rswz;
            float a[4][4];
            float b[4][8];
            {
                float4 t0 = *(const float4*)&As[tr + 0][ac];
                a[0][0] = t0.x; a[0][1] = t0.y; a[0][2] = t0.z; a[0][3] = t0.w;
                float4 t1 = *(const float4*)&As[tr + 1][ac];
                a[1][0] = t1.x; a[1][1] = t1.y; a[1][2] = t1.z; a[1][3] = t1.w;
                float4 t2 = *(const float4*)&As[tr + 2][ac];
                a[2][0] = t2.x; a[2][1] = t2.y; a[2][2] = t2.z; a[2][3] = t2.w;
                float4 t3 = *(const float4*)&As[tr + 3][ac];
                a[3][0] = t3.x; a[3][1] = t3.y; a[3][2] = t3.z; a[3][3] = t3.w;
            }
#pragma unroll
            for (int k = 0; k < 4; ++k) {
                float4 tl = *(const float4*)&Bs[kg * 4 + k][tc];
                float4 th = *(const float4*)&Bs[kg * 4 + k][tc + 4];
                b[k][0] = tl.x; b[k][1] = tl.y; b[k][2] = tl.z; b[k][3] = tl.w;
                b[k][4] = th.x; b[k][5] = th.y; b[k][6] = th.z; b[k][7] = th.w;
            }
#pragma unroll
            for (int i = 0; i < 4; ++i)
#pragma unroll
                for (int k = 0; k < 4; ++k)
#pragma unroll
                    for (int j = 0; j < 8; ++j)
                        acc[i][j] = fmaf(a[i][k], b[k][j], acc[i][j]);
        }
        __syncthreads();
    }
#pragma unroll
    for (int i = 0; i < 4; ++i) {
        int grow = row0 + tr + i;
        if (grow < n) {
            *(float4*)(C + (size_t)grow * HDIM + tc) =
                make_float4(acc[i][0], acc[i][1], acc[i][2], acc[i][3]);
            *(float4*)(C + (size_t)grow * HDIM + tc + 4) =
                make_float4(acc[i][4], acc[i][5], acc[i][6], acc[i][7]);
        }
    }
}

// ---------------- pull-style aggregation + self-loop + bias + relu ----------------
__global__ __launch_bounds__(256) void k_gather(const float* __restrict__ h,
                                                const int* __restrict__ off,
                                                const int* __restrict__ degi,
                                                const int2* __restrict__ eadj,
                                                const float* __restrict__ selfn,
                                                const float* __restrict__ bias,
                                                float* __restrict__ out, int n) {
    int t = blockIdx.x * 256 + threadIdx.x;
    int i = t >> 4;
    if (i >= n) return;
    int q = (t & 15) * 4;
    int e0 = off[i];
    int e1 = e0 + degi[i];
    float ax = 0.f, ay = 0.f, az = 0.f, aw = 0.f;
    float bx = 0.f, by = 0.f, bz = 0.f, bw = 0.f;
    int e = e0;
    for (; e + 1 < e1; e += 2) {       // unroll x2: two row loads in flight
        int2 p0 = eadj[e];
        int2 p1 = eadj[e + 1];
        float4 v0 = *(const float4*)(h + (size_t)p0.x * HDIM + q);
        float4 v1 = *(const float4*)(h + (size_t)p1.x * HDIM + q);
        float w0 = __int_as_float(p0.y);
        float w1 = __int_as_float(p1.y);
        ax = fmaf(v0.x, w0, ax); ay = fmaf(v0.y, w0, ay);
        az = fmaf(v0.z, w0, az); aw = fmaf(v0.w, w0, aw);
        bx = fmaf(v1.x, w1, bx); by = fmaf(v1.y, w1, by);
        bz = fmaf(v1.z, w1, bz); bw = fmaf(v1.w, w1, bw);
    }
    if (e < e1) {
        int2 p0 = eadj[e];
        float4 v0 = *(const float4*)(h + (size_t)p0.x * HDIM + q);
        float w0 = __int_as_float(p0.y);
        ax = fmaf(v0.x, w0, ax); ay = fmaf(v0.y, w0, ay);
        az = fmaf(v0.z, w0, az); aw = fmaf(v0.w, w0, aw);
    }
    ax += bx; ay += by; az += bz; aw += bw;
    float sn = selfn[i];
    float4 hv = *(const float4*)(h + (size_t)i * HDIM + q);
    float4 b = *(const float4*)(bias + q);
    ax = fmaf(hv.x, sn, ax) + b.x;
    ay = fmaf(hv.y, sn, ay) + b.y;
    az = fmaf(hv.z, sn, az) + b.z;
    aw = fmaf(hv.w, sn, aw) + b.w;
    *(float4*)(out + (size_t)i * HDIM + q) =
        make_float4(fmaxf(ax, 0.f), fmaxf(ay, 0.f), fmaxf(az, 0.f), fmaxf(aw, 0.f));
}

// ---------------- pool phase 1: partial sums, 8 segments per graph ----------------
__global__ __launch_bounds__(256) void k_pool_acc(const float* __restrict__ h,
                                                  const int* __restrict__ batch,
                                                  float* __restrict__ pooled, int n) {
    __shared__ float part[4][64];
    int g = blockIdx.x >> 3;
    int seg = blockIdx.x & 7;
    int t = threadIdx.x;
    int f = t & 63;
    int rg = t >> 6;
    int lo = 0, hi = n;
    while (lo < hi) { int m = (lo + hi) >> 1; if (batch[m] < g) lo = m + 1; else hi = m; }
    int s = lo;
    lo = 0; hi = n;
    while (lo < hi) { int m = (lo + hi) >> 1; if (batch[m] < g + 1) lo = m + 1; else hi = m; }
    int e2 = lo;
    int len = e2 - s;
    int chunk = (len + 7) >> 3;
    int i0 = s + seg * chunk;
    int i1 = min(i0 + chunk, e2);

    float sum = 0.f;
    for (int i = i0 + rg; i < i1; i += 4) sum += h[(size_t)i * HDIM + f];
    part[rg][f] = sum;
    __syncthreads();
    if (t < 64) {
        float tot = part[0][t] + part[1][t] + part[2][t] + part[3][t];
        if (tot != 0.f) atomicAdd(&pooled[g * HDIM + t], tot);
    }
}

// ---------------- pool phase 2: mean + linear head ----------------
__global__ __launch_bounds__(640) void k_head(const float* __restrict__ pooled,
                                              const int* __restrict__ batch,
                                              const float* __restrict__ linW,
                                              const float* __restrict__ linb,
                                              float* __restrict__ out, int n) {
    int t = threadIdx.x;
    if (t >= NGRAPH * NCLS) return;
    int g = t / NCLS;
    int c = t - g * NCLS;
    int lo = 0, hi = n;
    while (lo < hi) { int m = (lo + hi) >> 1; if (batch[m] < g) lo = m + 1; else hi = m; }
    int s = lo;
    lo = 0; hi = n;
    while (lo < hi) { int m = (lo + hi) >> 1; if (batch[m] < g + 1) lo = m + 1; else hi = m; }
    float inv = 1.0f / fmaxf((float)(lo - s), 1.0f);
    float acc = linb[c];
#pragma unroll
    for (int k = 0; k < HDIM; ++k)
        acc = fmaf(pooled[g * HDIM + k] * inv, linW[k * NCLS + c], acc);
    out[g * NCLS + c] = acc;
}

extern "C" void kernel_launch(void* const* d_in, const int* in_sizes, int n_in,
                              void* d_out, int out_size, void* d_ws, size_t ws_size,
                              hipStream_t stream) {
    (void)in_sizes; (void)n_in; (void)out_size; (void)ws_size;
    const float* x    = (const float*)d_in[0];
    const int*   ei   = (const int*)d_in[1];
    const int*   batch= (const int*)d_in[2];
    const float* W1   = (const float*)d_in[3];
    const float* b1   = (const float*)d_in[4];
    const float* W2   = (const float*)d_in[5];
    const float* b2   = (const float*)d_in[6];
    const float* W3   = (const float*)d_in[7];
    const float* b3   = (const float*)d_in[8];
    const float* linW = (const float*)d_in[9];
    const float* linb = (const float*)d_in[10];
    float* out = (float*)d_out;

    const int N = N_NODES, E = N_EDGES;
    const int* src = ei;
    const int* dst = ei + E;

    char* ws = (char*)d_ws;
    float* hA     = (float*)ws; ws += (size_t)N * HDIM * 4;
    float* hB     = (float*)ws; ws += (size_t)N * HDIM * 4;
    float* dis    = (float*)ws; ws += (size_t)N * 4;
    float* selfn  = (float*)ws; ws += (size_t)N * 4;
    int2*  eadj   = (int2*)ws;  ws += (size_t)E * 8;
    int*   degi   = (int*)ws;   ws += (size_t)N * 4;
    int*   off    = (int*)ws;   ws += (size_t)N * 4;
    int*   bcur   = (int*)ws;   ws += (size_t)NBUCK * 4;
    float* pooled = (float*)ws; ws += (size_t)NGRAPH * HDIM * 4;
    int*   bsum   = (int*)ws;   ws += 256 * 4;
    int*   stage  = (int*)hA;   // aliased: consumed by k_csr before gemm1 writes hA

    const int nbN = (N + 255) / 256;   // 196
    const int nbE = (E + 255) / 256;   // 3125
    const int gb  = (N + 127) / 128;   // 391
    const int ngth = (N * 16 + 255) / 256;

    hipMemsetAsync(degi, 0, (size_t)N * 4, stream);
    hipMemsetAsync(pooled, 0, (size_t)NGRAPH * HDIM * 4, stream);
    k_deg_count<<<nbE, 256, 0, stream>>>(dst, degi, E);
    k_scan1<<<nbN, 256, 0, stream>>>(degi, off, bsum, N);
    k_scan2<<<1, 256, 0, stream>>>(bsum, nbN);
    k_scan3<<<nbN, 256, 0, stream>>>(off, bcur, bsum, degi, dis, selfn, N);
    k_part<<<(E + 4095) / 4096, 256, 0, stream>>>(src, dst, bcur, stage, E);
    k_csr<<<NBUCK, 256, 0, stream>>>(stage, off, dis, eadj, E, N);

    // layer 1
    k_gemm<F_INPUT><<<gb, 256, 0, stream>>>(x, W1, hA, N);
    k_gather<<<ngth, 256, 0, stream>>>(hA, off, degi, eadj, selfn, b1, hB, N);
    // layer 2
    k_gemm<HDIM><<<gb, 256, 0, stream>>>(hB, W2, hA, N);
    k_gather<<<ngth, 256, 0, stream>>>(hA, off, degi, eadj, selfn, b2, hB, N);
    // layer 3
    k_gemm<HDIM><<<gb, 256, 0, stream>>>(hB, W3, hA, N);
    k_gather<<<ngth, 256, 0, stream>>>(hA, off, degi, eadj, selfn, b3, hB, N);
    // pool + head
    k_pool_acc<<<NGRAPH * 8, 256, 0, stream>>>(hB, batch, pooled, N);
    k_head<<<1, 640, 0, stream>>>(pooled, batch, linW, linb, out, N);
}

// Round 7
// 393.755 us; speedup vs baseline: 1.6082x; 1.6082x over previous
//
#include <hip/hip_runtime.h>

#define N_NODES 50000
#define N_EDGES 800000
#define F_INPUT 256
#define HDIM 64
#define NCLS 10
#define NGRAPH 64

#define BSHIFT 7                 // 128 nodes per bucket
#define NBUCK 391                // ceil(50000/128)
#define CAP 2688                 // bucket edge capacity (mean 2048, sigma ~45)

// ---------------- degree histogram ----------------
__global__ __launch_bounds__(256) void k_deg_count(const int* __restrict__ dst,
                                                   int* __restrict__ degi, int E) {
    int e = blockIdx.x * 256 + threadIdx.x;
    if (e < E) atomicAdd(&degi[dst[e]], 1);
}

// ---------------- prefix sum (3-phase) ----------------
__global__ __launch_bounds__(256) void k_scan1(const int* __restrict__ degi,
                                               int* __restrict__ off,
                                               int* __restrict__ bsum, int n) {
    __shared__ int tmp[256];
    int t = threadIdx.x;
    int i = blockIdx.x * 256 + t;
    int v = (i < n) ? degi[i] : 0;
    tmp[t] = v;
    __syncthreads();
    for (int d = 1; d < 256; d <<= 1) {
        int x = (t >= d) ? tmp[t - d] : 0;
        __syncthreads();
        tmp[t] += x;
        __syncthreads();
    }
    if (i < n) off[i] = tmp[t] - v;        // exclusive within block
    if (t == 255) bsum[blockIdx.x] = tmp[t];
}

__global__ __launch_bounds__(256) void k_scan2(int* __restrict__ bsum, int nb) {
    __shared__ int tmp[256];
    int t = threadIdx.x;
    int v = (t < nb) ? bsum[t] : 0;
    tmp[t] = v;
    __syncthreads();
    for (int d = 1; d < 256; d <<= 1) {
        int x = (t >= d) ? tmp[t - d] : 0;
        __syncthreads();
        tmp[t] += x;
        __syncthreads();
    }
    if (t < nb) bsum[t] = tmp[t] - v;      // exclusive block bases
}

// scan finalize + GCN norm factors + bucket cursor seed (fused)
__global__ __launch_bounds__(256) void k_scan3(int* __restrict__ off,
                                               int* __restrict__ bcur,
                                               const int* __restrict__ bsum,
                                               const int* __restrict__ degi,
                                               float* __restrict__ dis,
                                               float* __restrict__ selfn, int n) {
    int i = blockIdx.x * 256 + threadIdx.x;
    if (i < n) {
        int o = off[i] + bsum[blockIdx.x];
        off[i] = o;
        if ((i & 127) == 0) bcur[i >> BSHIFT] = o;   // bucket region start
        float d = (float)(degi[i] + 1);
        dis[i] = rsqrtf(d);
        selfn[i] = 1.0f / d;
    }
}

// ---------------- pass A: LDS-staged bucket partition ----------------
__global__ __launch_bounds__(256) void k_part(const int* __restrict__ src,
                                              const int* __restrict__ dst,
                                              int* __restrict__ bcur,
                                              int* __restrict__ stage, int E) {
    __shared__ int cnt[NBUCK];
    __shared__ int base[NBUCK];
    const int tid = threadIdx.x;
    const int e0 = blockIdx.x * 4096;
    int pb[16], pv[16];
    for (int t = tid; t < NBUCK; t += 256) cnt[t] = 0;
    __syncthreads();
#pragma unroll
    for (int j = 0; j < 16; ++j) {
        int e = e0 + j * 256 + tid;
        if (e < E) {
            int s = src[e], d = dst[e];
            pb[j] = d >> BSHIFT;
            pv[j] = (s << BSHIFT) | (d & 127);
            atomicAdd(&cnt[pb[j]], 1);
        } else pb[j] = -1;
    }
    __syncthreads();
    for (int t = tid; t < NBUCK; t += 256) {
        int c = cnt[t];
        base[t] = c ? atomicAdd(&bcur[t], c) : 0;
        cnt[t] = 0;
    }
    __syncthreads();
#pragma unroll
    for (int j = 0; j < 16; ++j) {
        if (pb[j] >= 0) {
            int r = atomicAdd(&cnt[pb[j]], 1);
            stage[base[pb[j]] + r] = pv[j];
        }
    }
}

// ---------------- pass B: per-bucket LDS counting sort -> CSR ----------------
__global__ __launch_bounds__(256) void k_csr(const int* __restrict__ stage,
                                             const int* __restrict__ off,
                                             const float* __restrict__ dis,
                                             int2* __restrict__ eadj, int E, int n) {
    __shared__ int lcur[128];
    __shared__ int2 ebuf[CAP];
    const int b = blockIdx.x;
    const int tid = threadIdx.x;
    const int n0 = b << BSHIFT;
    const int nn = min(128, n - n0);
    const int r0 = off[n0];
    const int r1 = (b == NBUCK - 1) ? E : off[n0 + 128];
    const int len = r1 - r0;
    if (tid < nn) lcur[tid] = off[n0 + tid] - r0;
    __syncthreads();
    const bool fits = (len <= CAP);
    for (int j = r0 + tid; j < r1; j += 256) {
        int p = stage[j];
        int s = p >> BSHIFT;
        int dl = p & 127;
        float w = dis[s] * dis[n0 + dl];
        int rk = atomicAdd(&lcur[dl], 1);
        int2 v = make_int2(s, __float_as_int(w));
        if (fits) ebuf[rk] = v;
        else eadj[r0 + rk] = v;          // statistical-overflow fallback
    }
    __syncthreads();
    if (fits)
        for (int j = tid; j < len; j += 256) eadj[r0 + j] = ebuf[j];
}

// ---------------- fp32 GEMM: C[n,64] = A[n,K] @ B[K,64] ----------------
// 128x64 tile, 128 threads (16x8), 8x8 micro-tile, all-b128 LDS reads.
// LDS model (ds_read_b128 ~12cyc/wave-inst, 1 pipe/CU vs 4 SIMDs):
//   per kg: FMA 2*M*N=128 CU-cyc vs LDS 12*(M+N)=192 cyc -> 1.5x LDS-bound
//   (4x8 was 2.25x; scalar reads 3x). acc=64 regs.
// ANTI-SPILL (rounds 5-6 lesson): kg loop is `#pragma unroll 1` — full unroll
// software-pipelines 16 float4 temps x 16 iters and spills acc to scratch
// (VGPR 256, FETCH 165MB). Flat scalar temps, constant indices only.
template <int K>
__global__ __launch_bounds__(128) void k_gemm(const float* __restrict__ A,
                                              const float* __restrict__ B,
                                              float* __restrict__ C, int n) {
    __shared__ float As[128][68];
    __shared__ float Bs[64][64];
    const int tid = threadIdx.x;
    const int row0 = blockIdx.x * 128;
    const int tx = tid & 7;          // col group 0..7 -> 8 cols
    const int ty = tid >> 3;         // row group 0..15 -> 8 rows
    const int tr = ty * 8;
    const int tc = tx * 8;
    const int lk = (tid & 15) * 4;   // staging k/col offset
    const int lr = tid >> 4;         // staging row 0..7
    const int swz0 = (((tr >> 2) & 7) << 2);       // rows tr..tr+3
    const int swz1 = ((((tr + 4) >> 2) & 7) << 2); // rows tr+4..tr+7

    float acc[8][8];
#pragma unroll
    for (int i = 0; i < 8; ++i)
#pragma unroll
        for (int j = 0; j < 8; ++j) acc[i][j] = 0.0f;

    for (int kc = 0; kc < K; kc += 64) {
        // stage A: 128 rows x 64 k (XOR column swizzle per 4-row band)
#pragma unroll
        for (int p = 0; p < 16; ++p) {
            int r = lr + p * 8;
            int grow = row0 + r;
            float4 v = make_float4(0.f, 0.f, 0.f, 0.f);
            if (grow < n) v = *(const float4*)(A + (size_t)grow * K + kc + lk);
            *(float4*)&As[r][lk ^ (((r >> 2) & 7) << 2)] = v;
        }
        // stage B: 64 k x 64 cols
#pragma unroll
        for (int p = 0; p < 8; ++p) {
            int kk = lr + p * 8;
            *(float4*)&Bs[kk][lk] = *(const float4*)(B + (size_t)(kc + kk) * HDIM + lk);
        }
        __syncthreads();
#pragma unroll 1
        for (int kg = 0; kg < 16; ++kg) {
            const int ac0 = (kg * 4) ^ swz0;
            const int ac1 = (kg * 4) ^ swz1;
            float a[8][4];
            float b[4][8];
            {
                float4 t0 = *(const float4*)&As[tr + 0][ac0];
                a[0][0] = t0.x; a[0][1] = t0.y; a[0][2] = t0.z; a[0][3] = t0.w;
                float4 t1 = *(const float4*)&As[tr + 1][ac0];
                a[1][0] = t1.x; a[1][1] = t1.y; a[1][2] = t1.z; a[1][3] = t1.w;
                float4 t2 = *(const float4*)&As[tr + 2][ac0];
                a[2][0] = t2.x; a[2][1] = t2.y; a[2][2] = t2.z; a[2][3] = t2.w;
                float4 t3 = *(const float4*)&As[tr + 3][ac0];
                a[3][0] = t3.x; a[3][1] = t3.y; a[3][2] = t3.z; a[3][3] = t3.w;
                float4 t4 = *(const float4*)&As[tr + 4][ac1];
                a[4][0] = t4.x; a[4][1] = t4.y; a[4][2] = t4.z; a[4][3] = t4.w;
                float4 t5 = *(const float4*)&As[tr + 5][ac1];
                a[5][0] = t5.x; a[5][1] = t5.y; a[5][2] = t5.z; a[5][3] = t5.w;
                float4 t6 = *(const float4*)&As[tr + 6][ac1];
                a[6][0] = t6.x; a[6][1] = t6.y; a[6][2] = t6.z; a[6][3] = t6.w;
                float4 t7 = *(const float4*)&As[tr + 7][ac1];
                a[7][0] = t7.x; a[7][1] = t7.y; a[7][2] = t7.z; a[7][3] = t7.w;
            }
#pragma unroll
            for (int k = 0; k < 4; ++k) {
                float4 tl = *(const float4*)&Bs[kg * 4 + k][tc];
                float4 th = *(const float4*)&Bs[kg * 4 + k][tc + 4];
                b[k][0] = tl.x; b[k][1] = tl.y; b[k][2] = tl.z; b[k][3] = tl.w;
                b[k][4] = th.x; b[k][5] = th.y; b[k][6] = th.z; b[k][7] = th.w;
            }
#pragma unroll
            for (int i = 0; i < 8; ++i)
#pragma unroll
                for (int k = 0; k < 4; ++k)
#pragma unroll
                    for (int j = 0; j < 8; ++j)
                        acc[i][j] = fmaf(a[i][k], b[k][j], acc[i][j]);
        }
        __syncthreads();
    }
#pragma unroll
    for (int i = 0; i < 8; ++i) {
        int grow = row0 + tr + i;
        if (grow < n) {
            *(float4*)(C + (size_t)grow * HDIM + tc) =
                make_float4(acc[i][0], acc[i][1], acc[i][2], acc[i][3]);
            *(float4*)(C + (size_t)grow * HDIM + tc + 4) =
                make_float4(acc[i][4], acc[i][5], acc[i][6], acc[i][7]);
        }
    }
}

// ---------------- pull-style aggregation + self-loop + bias + relu ----------------
__global__ __launch_bounds__(256) void k_gather(const float* __restrict__ h,
                                                const int* __restrict__ off,
                                                const int* __restrict__ degi,
                                                const int2* __restrict__ eadj,
                                                const float* __restrict__ selfn,
                                                const float* __restrict__ bias,
                                                float* __restrict__ out, int n) {
    int t = blockIdx.x * 256 + threadIdx.x;
    int i = t >> 4;
    if (i >= n) return;
    int q = (t & 15) * 4;
    int e0 = off[i];
    int e1 = e0 + degi[i];
    float ax = 0.f, ay = 0.f, az = 0.f, aw = 0.f;
    float bx = 0.f, by = 0.f, bz = 0.f, bw = 0.f;
    int e = e0;
    for (; e + 1 < e1; e += 2) {       // unroll x2: two row loads in flight
        int2 p0 = eadj[e];
        int2 p1 = eadj[e + 1];
        float4 v0 = *(const float4*)(h + (size_t)p0.x * HDIM + q);
        float4 v1 = *(const float4*)(h + (size_t)p1.x * HDIM + q);
        float w0 = __int_as_float(p0.y);
        float w1 = __int_as_float(p1.y);
        ax = fmaf(v0.x, w0, ax); ay = fmaf(v0.y, w0, ay);
        az = fmaf(v0.z, w0, az); aw = fmaf(v0.w, w0, aw);
        bx = fmaf(v1.x, w1, bx); by = fmaf(v1.y, w1, by);
        bz = fmaf(v1.z, w1, bz); bw = fmaf(v1.w, w1, bw);
    }
    if (e < e1) {
        int2 p0 = eadj[e];
        float4 v0 = *(const float4*)(h + (size_t)p0.x * HDIM + q);
        float w0 = __int_as_float(p0.y);
        ax = fmaf(v0.x, w0, ax); ay = fmaf(v0.y, w0, ay);
        az = fmaf(v0.z, w0, az); aw = fmaf(v0.w, w0, aw);
    }
    ax += bx; ay += by; az += bz; aw += bw;
    float sn = selfn[i];
    float4 hv = *(const float4*)(h + (size_t)i * HDIM + q);
    float4 b = *(const float4*)(bias + q);
    ax = fmaf(hv.x, sn, ax) + b.x;
    ay = fmaf(hv.y, sn, ay) + b.y;
    az = fmaf(hv.z, sn, az) + b.z;
    aw = fmaf(hv.w, sn, aw) + b.w;
    *(float4*)(out + (size_t)i * HDIM + q) =
        make_float4(fmaxf(ax, 0.f), fmaxf(ay, 0.f), fmaxf(az, 0.f), fmaxf(aw, 0.f));
}

// ---------------- pool phase 1: partial sums, 8 segments per graph ----------------
__global__ __launch_bounds__(256) void k_pool_acc(const float* __restrict__ h,
                                                  const int* __restrict__ batch,
                                                  float* __restrict__ pooled, int n) {
    __shared__ float part[4][64];
    int g = blockIdx.x >> 3;
    int seg = blockIdx.x & 7;
    int t = threadIdx.x;
    int f = t & 63;
    int rg = t >> 6;
    int lo = 0, hi = n;
    while (lo < hi) { int m = (lo + hi) >> 1; if (batch[m] < g) lo = m + 1; else hi = m; }
    int s = lo;
    lo = 0; hi = n;
    while (lo < hi) { int m = (lo + hi) >> 1; if (batch[m] < g + 1) lo = m + 1; else hi = m; }
    int e2 = lo;
    int len = e2 - s;
    int chunk = (len + 7) >> 3;
    int i0 = s + seg * chunk;
    int i1 = min(i0 + chunk, e2);

    float sum = 0.f;
    for (int i = i0 + rg; i < i1; i += 4) sum += h[(size_t)i * HDIM + f];
    part[rg][f] = sum;
    __syncthreads();
    if (t < 64) {
        float tot = part[0][t] + part[1][t] + part[2][t] + part[3][t];
        if (tot != 0.f) atomicAdd(&pooled[g * HDIM + t], tot);
    }
}

// ---------------- pool phase 2: mean + linear head ----------------
__global__ __launch_bounds__(640) void k_head(const float* __restrict__ pooled,
                                              const int* __restrict__ batch,
                                              const float* __restrict__ linW,
                                              const float* __restrict__ linb,
                                              float* __restrict__ out, int n) {
    int t = threadIdx.x;
    if (t >= NGRAPH * NCLS) return;
    int g = t / NCLS;
    int c = t - g * NCLS;
    int lo = 0, hi = n;
    while (lo < hi) { int m = (lo + hi) >> 1; if (batch[m] < g) lo = m + 1; else hi = m; }
    int s = lo;
    lo = 0; hi = n;
    while (lo < hi) { int m = (lo + hi) >> 1; if (batch[m] < g + 1) lo = m + 1; else hi = m; }
    float inv = 1.0f / fmaxf((float)(lo - s), 1.0f);
    float acc = linb[c];
#pragma unroll
    for (int k = 0; k < HDIM; ++k)
        acc = fmaf(pooled[g * HDIM + k] * inv, linW[k * NCLS + c], acc);
    out[g * NCLS + c] = acc;
}

extern "C" void kernel_launch(void* const* d_in, const int* in_sizes, int n_in,
                              void* d_out, int out_size, void* d_ws, size_t ws_size,
                              hipStream_t stream) {
    (void)in_sizes; (void)n_in; (void)out_size; (void)ws_size;
    const float* x    = (const float*)d_in[0];
    const int*   ei   = (const int*)d_in[1];
    const int*   batch= (const int*)d_in[2];
    const float* W1   = (const float*)d_in[3];
    const float* b1   = (const float*)d_in[4];
    const float* W2   = (const float*)d_in[5];
    const float* b2   = (const float*)d_in[6];
    const float* W3   = (const float*)d_in[7];
    const float* b3   = (const float*)d_in[8];
    const float* linW = (const float*)d_in[9];
    const float* linb = (const float*)d_in[10];
    float* out = (float*)d_out;

    const int N = N_NODES, E = N_EDGES;
    const int* src = ei;
    const int* dst = ei + E;

    char* ws = (char*)d_ws;
    float* hA     = (float*)ws; ws += (size_t)N * HDIM * 4;
    float* hB     = (float*)ws; ws += (size_t)N * HDIM * 4;
    float* dis    = (float*)ws; ws += (size_t)N * 4;
    float* selfn  = (float*)ws; ws += (size_t)N * 4;
    int2*  eadj   = (int2*)ws;  ws += (size_t)E * 8;
    int*   degi   = (int*)ws;   ws += (size_t)N * 4;
    int*   off    = (int*)ws;   ws += (size_t)N * 4;
    int*   bcur   = (int*)ws;   ws += (size_t)NBUCK * 4;
    float* pooled = (float*)ws; ws += (size_t)NGRAPH * HDIM * 4;
    int*   bsum   = (int*)ws;   ws += 256 * 4;
    int*   stage  = (int*)hA;   // aliased: consumed by k_csr before gemm1 writes hA

    const int nbN = (N + 255) / 256;   // 196
    const int nbE = (E + 255) / 256;   // 3125
    const int gb  = (N + 127) / 128;   // 391
    const int ngth = (N * 16 + 255) / 256;

    hipMemsetAsync(degi, 0, (size_t)N * 4, stream);
    hipMemsetAsync(pooled, 0, (size_t)NGRAPH * HDIM * 4, stream);
    k_deg_count<<<nbE, 256, 0, stream>>>(dst, degi, E);
    k_scan1<<<nbN, 256, 0, stream>>>(degi, off, bsum, N);
    k_scan2<<<1, 256, 0, stream>>>(bsum, nbN);
    k_scan3<<<nbN, 256, 0, stream>>>(off, bcur, bsum, degi, dis, selfn, N);
    k_part<<<(E + 4095) / 4096, 256, 0, stream>>>(src, dst, bcur, stage, E);
    k_csr<<<NBUCK, 256, 0, stream>>>(stage, off, dis, eadj, E, N);

    // layer 1
    k_gemm<F_INPUT><<<gb, 128, 0, stream>>>(x, W1, hA, N);
    k_gather<<<ngth, 256, 0, stream>>>(hA, off, degi, eadj, selfn, b1, hB, N);
    // layer 2
    k_gemm<HDIM><<<gb, 128, 0, stream>>>(hB, W2, hA, N);
    k_gather<<<ngth, 256, 0, stream>>>(hA, off, degi, eadj, selfn, b2, hB, N);
    // layer 3
    k_gemm<HDIM><<<gb, 128, 0, stream>>>(hB, W3, hA, N);
    k_gather<<<ngth, 256, 0, stream>>>(hA, off, degi, eadj, selfn, b3, hB, N);
    // pool + head
    k_pool_acc<<<NGRAPH * 8, 256, 0, stream>>>(hB, batch, pooled, N);
    k_head<<<1, 640, 0, stream>>>(pooled, batch, linW, linb, out, N);
}

// Round 8
// 373.150 us; speedup vs baseline: 1.6970x; 1.0552x over previous
//
#include <hip/hip_runtime.h>

#define N_NODES 50000
#define N_EDGES 800000
#define F_INPUT 256
#define HDIM 64
#define NCLS 10
#define NGRAPH 64

#define BSHIFT 7                 // 128 nodes per bucket
#define NBUCK 391                // ceil(50000/128)
#define CAP 2688                 // bucket edge capacity (mean 2048, sigma ~45)

// ---------------- degree histogram ----------------
__global__ __launch_bounds__(256) void k_deg_count(const int* __restrict__ dst,
                                                   int* __restrict__ degi, int E) {
    int e = blockIdx.x * 256 + threadIdx.x;
    if (e < E) atomicAdd(&degi[dst[e]], 1);
}

// ---------------- prefix sum (3-phase) ----------------
__global__ __launch_bounds__(256) void k_scan1(const int* __restrict__ degi,
                                               int* __restrict__ off,
                                               int* __restrict__ bsum, int n) {
    __shared__ int tmp[256];
    int t = threadIdx.x;
    int i = blockIdx.x * 256 + t;
    int v = (i < n) ? degi[i] : 0;
    tmp[t] = v;
    __syncthreads();
    for (int d = 1; d < 256; d <<= 1) {
        int x = (t >= d) ? tmp[t - d] : 0;
        __syncthreads();
        tmp[t] += x;
        __syncthreads();
    }
    if (i < n) off[i] = tmp[t] - v;        // exclusive within block
    if (t == 255) bsum[blockIdx.x] = tmp[t];
}

__global__ __launch_bounds__(256) void k_scan2(int* __restrict__ bsum, int nb) {
    __shared__ int tmp[256];
    int t = threadIdx.x;
    int v = (t < nb) ? bsum[t] : 0;
    tmp[t] = v;
    __syncthreads();
    for (int d = 1; d < 256; d <<= 1) {
        int x = (t >= d) ? tmp[t - d] : 0;
        __syncthreads();
        tmp[t] += x;
        __syncthreads();
    }
    if (t < nb) bsum[t] = tmp[t] - v;      // exclusive block bases
}

// scan finalize + GCN norm factors + bucket cursor seed (fused)
__global__ __launch_bounds__(256) void k_scan3(int* __restrict__ off,
                                               int* __restrict__ bcur,
                                               const int* __restrict__ bsum,
                                               const int* __restrict__ degi,
                                               float* __restrict__ dis,
                                               float* __restrict__ selfn, int n) {
    int i = blockIdx.x * 256 + threadIdx.x;
    if (i < n) {
        int o = off[i] + bsum[blockIdx.x];
        off[i] = o;
        if ((i & 127) == 0) bcur[i >> BSHIFT] = o;   // bucket region start
        float d = (float)(degi[i] + 1);
        dis[i] = rsqrtf(d);
        selfn[i] = 1.0f / d;
    }
}

// ---------------- pass A: LDS-staged bucket partition ----------------
__global__ __launch_bounds__(256) void k_part(const int* __restrict__ src,
                                              const int* __restrict__ dst,
                                              int* __restrict__ bcur,
                                              int* __restrict__ stage, int E) {
    __shared__ int cnt[NBUCK];
    __shared__ int base[NBUCK];
    const int tid = threadIdx.x;
    const int e0 = blockIdx.x * 4096;
    int pb[16], pv[16];
    for (int t = tid; t < NBUCK; t += 256) cnt[t] = 0;
    __syncthreads();
#pragma unroll
    for (int j = 0; j < 16; ++j) {
        int e = e0 + j * 256 + tid;
        if (e < E) {
            int s = src[e], d = dst[e];
            pb[j] = d >> BSHIFT;
            pv[j] = (s << BSHIFT) | (d & 127);
            atomicAdd(&cnt[pb[j]], 1);
        } else pb[j] = -1;
    }
    __syncthreads();
    for (int t = tid; t < NBUCK; t += 256) {
        int c = cnt[t];
        base[t] = c ? atomicAdd(&bcur[t], c) : 0;
        cnt[t] = 0;
    }
    __syncthreads();
#pragma unroll
    for (int j = 0; j < 16; ++j) {
        if (pb[j] >= 0) {
            int r = atomicAdd(&cnt[pb[j]], 1);
            stage[base[pb[j]] + r] = pv[j];
        }
    }
}

// ---------------- pass B: per-bucket LDS counting sort -> CSR ----------------
__global__ __launch_bounds__(256) void k_csr(const int* __restrict__ stage,
                                             const int* __restrict__ off,
                                             const float* __restrict__ dis,
                                             int2* __restrict__ eadj, int E, int n) {
    __shared__ int lcur[128];
    __shared__ int2 ebuf[CAP];
    const int b = blockIdx.x;
    const int tid = threadIdx.x;
    const int n0 = b << BSHIFT;
    const int nn = min(128, n - n0);
    const int r0 = off[n0];
    const int r1 = (b == NBUCK - 1) ? E : off[n0 + 128];
    const int len = r1 - r0;
    if (tid < nn) lcur[tid] = off[n0 + tid] - r0;
    __syncthreads();
    const bool fits = (len <= CAP);
    for (int j = r0 + tid; j < r1; j += 256) {
        int p = stage[j];
        int s = p >> BSHIFT;
        int dl = p & 127;
        float w = dis[s] * dis[n0 + dl];
        int rk = atomicAdd(&lcur[dl], 1);
        int2 v = make_int2(s, __float_as_int(w));
        if (fits) ebuf[rk] = v;
        else eadj[r0 + rk] = v;          // statistical-overflow fallback
    }
    __syncthreads();
    if (fits)
        for (int j = tid; j < len; j += 256) eadj[r0 + j] = ebuf[j];
}

// ---------------- fp32 GEMM: C[n,64] = A[n,FULLK] @ B[FULLK,64] ----------------
// Round-4 proven config: 64x64 tile, 256 threads (16x16), 4x4 micro-tile,
// float4 LDS reads, 68-pad (zero conflicts measured), VGPR 68 (no spill).
// Split-K via blockIdx.y: block y computes K-range [y*KTILES*64, ...), writing
// C + y*N*HDIM. For layer 1 (K=256) grid (782,2) doubles resident waves
// (occupancy was the binding constraint: 7-20% across rounds 2-7).
template <int FULLK, int KTILES>
__global__ __launch_bounds__(256) void k_gemm(const float* __restrict__ A,
                                              const float* __restrict__ B,
                                              float* __restrict__ C, int n) {
    __shared__ float As[64][68];
    __shared__ float Bs[64][64];
    const int tid = threadIdx.x;
    const int row0 = blockIdx.x * 64;
    const int kbase = blockIdx.y * (KTILES * 64);
    const size_t coff = (size_t)blockIdx.y * N_NODES * HDIM;
    const int tx = tid & 15;
    const int ty = tid >> 4;
    const int tr = ty * 4;
    const int tc = tx * 4;
    const int lr = ty;
    const int lk = tx * 4;

    float acc[4][4];
#pragma unroll
    for (int i = 0; i < 4; ++i)
#pragma unroll
        for (int j = 0; j < 4; ++j) acc[i][j] = 0.0f;

    for (int kt = 0; kt < KTILES; ++kt) {
        const int kc = kbase + kt * 64;
#pragma unroll
        for (int j = 0; j < 4; ++j) {
            int r = lr + 16 * j;
            int grow = row0 + r;
            float4 v = make_float4(0.f, 0.f, 0.f, 0.f);
            if (grow < n) v = *(const float4*)(A + (size_t)grow * FULLK + kc + lk);
            *(float4*)&As[r][lk] = v;
        }
#pragma unroll
        for (int j = 0; j < 4; ++j) {
            int kk = lr + 16 * j;
            *(float4*)&Bs[kk][lk] = *(const float4*)(B + (size_t)(kc + kk) * HDIM + lk);
        }
        __syncthreads();
#pragma unroll
        for (int kg = 0; kg < 16; ++kg) {
            float4 b0 = *(const float4*)&Bs[kg * 4 + 0][tc];
            float4 b1 = *(const float4*)&Bs[kg * 4 + 1][tc];
            float4 b2 = *(const float4*)&Bs[kg * 4 + 2][tc];
            float4 b3 = *(const float4*)&Bs[kg * 4 + 3][tc];
#pragma unroll
            for (int i = 0; i < 4; ++i) {
                float4 av = *(const float4*)&As[tr + i][kg * 4];
                acc[i][0] = fmaf(av.x, b0.x, acc[i][0]);
                acc[i][1] = fmaf(av.x, b0.y, acc[i][1]);
                acc[i][2] = fmaf(av.x, b0.z, acc[i][2]);
                acc[i][3] = fmaf(av.x, b0.w, acc[i][3]);
                acc[i][0] = fmaf(av.y, b1.x, acc[i][0]);
                acc[i][1] = fmaf(av.y, b1.y, acc[i][1]);
                acc[i][2] = fmaf(av.y, b1.z, acc[i][2]);
                acc[i][3] = fmaf(av.y, b1.w, acc[i][3]);
                acc[i][0] = fmaf(av.z, b2.x, acc[i][0]);
                acc[i][1] = fmaf(av.z, b2.y, acc[i][1]);
                acc[i][2] = fmaf(av.z, b2.z, acc[i][2]);
                acc[i][3] = fmaf(av.z, b2.w, acc[i][3]);
                acc[i][0] = fmaf(av.w, b3.x, acc[i][0]);
                acc[i][1] = fmaf(av.w, b3.y, acc[i][1]);
                acc[i][2] = fmaf(av.w, b3.z, acc[i][2]);
                acc[i][3] = fmaf(av.w, b3.w, acc[i][3]);
            }
        }
        __syncthreads();
    }
#pragma unroll
    for (int i = 0; i < 4; ++i) {
        int grow = row0 + tr + i;
        if (grow < n) {
            *(float4*)(C + coff + (size_t)grow * HDIM + tc) =
                make_float4(acc[i][0], acc[i][1], acc[i][2], acc[i][3]);
        }
    }
}

// ---------------- split-K reduction: a += b (float4) ----------------
__global__ __launch_bounds__(256) void k_sum(float4* __restrict__ a,
                                             const float4* __restrict__ b, int n4) {
    int i = blockIdx.x * 256 + threadIdx.x;
    if (i < n4) {
        float4 x = a[i], y = b[i];
        a[i] = make_float4(x.x + y.x, x.y + y.y, x.z + y.z, x.w + y.w);
    }
}

// ---------------- pull-style aggregation + self-loop + bias + relu ----------------
__global__ __launch_bounds__(256) void k_gather(const float* __restrict__ h,
                                                const int* __restrict__ off,
                                                const int* __restrict__ degi,
                                                const int2* __restrict__ eadj,
                                                const float* __restrict__ selfn,
                                                const float* __restrict__ bias,
                                                float* __restrict__ out, int n) {
    int t = blockIdx.x * 256 + threadIdx.x;
    int i = t >> 4;
    if (i >= n) return;
    int q = (t & 15) * 4;
    int e0 = off[i];
    int e1 = e0 + degi[i];
    float ax = 0.f, ay = 0.f, az = 0.f, aw = 0.f;
    float bx = 0.f, by = 0.f, bz = 0.f, bw = 0.f;
    int e = e0;
    for (; e + 1 < e1; e += 2) {       // unroll x2: two row loads in flight
        int2 p0 = eadj[e];
        int2 p1 = eadj[e + 1];
        float4 v0 = *(const float4*)(h + (size_t)p0.x * HDIM + q);
        float4 v1 = *(const float4*)(h + (size_t)p1.x * HDIM + q);
        float w0 = __int_as_float(p0.y);
        float w1 = __int_as_float(p1.y);
        ax = fmaf(v0.x, w0, ax); ay = fmaf(v0.y, w0, ay);
        az = fmaf(v0.z, w0, az); aw = fmaf(v0.w, w0, aw);
        bx = fmaf(v1.x, w1, bx); by = fmaf(v1.y, w1, by);
        bz = fmaf(v1.z, w1, bz); bw = fmaf(v1.w, w1, bw);
    }
    if (e < e1) {
        int2 p0 = eadj[e];
        float4 v0 = *(const float4*)(h + (size_t)p0.x * HDIM + q);
        float w0 = __int_as_float(p0.y);
        ax = fmaf(v0.x, w0, ax); ay = fmaf(v0.y, w0, ay);
        az = fmaf(v0.z, w0, az); aw = fmaf(v0.w, w0, aw);
    }
    ax += bx; ay += by; az += bz; aw += bw;
    float sn = selfn[i];
    float4 hv = *(const float4*)(h + (size_t)i * HDIM + q);
    float4 b = *(const float4*)(bias + q);
    ax = fmaf(hv.x, sn, ax) + b.x;
    ay = fmaf(hv.y, sn, ay) + b.y;
    az = fmaf(hv.z, sn, az) + b.z;
    aw = fmaf(hv.w, sn, aw) + b.w;
    *(float4*)(out + (size_t)i * HDIM + q) =
        make_float4(fmaxf(ax, 0.f), fmaxf(ay, 0.f), fmaxf(az, 0.f), fmaxf(aw, 0.f));
}

// ---------------- pool phase 1: partial sums, 8 segments per graph ----------------
__global__ __launch_bounds__(256) void k_pool_acc(const float* __restrict__ h,
                                                  const int* __restrict__ batch,
                                                  float* __restrict__ pooled, int n) {
    __shared__ float part[4][64];
    int g = blockIdx.x >> 3;
    int seg = blockIdx.x & 7;
    int t = threadIdx.x;
    int f = t & 63;
    int rg = t >> 6;
    int lo = 0, hi = n;
    while (lo < hi) { int m = (lo + hi) >> 1; if (batch[m] < g) lo = m + 1; else hi = m; }
    int s = lo;
    lo = 0; hi = n;
    while (lo < hi) { int m = (lo + hi) >> 1; if (batch[m] < g + 1) lo = m + 1; else hi = m; }
    int e2 = lo;
    int len = e2 - s;
    int chunk = (len + 7) >> 3;
    int i0 = s + seg * chunk;
    int i1 = min(i0 + chunk, e2);

    float sum = 0.f;
    for (int i = i0 + rg; i < i1; i += 4) sum += h[(size_t)i * HDIM + f];
    part[rg][f] = sum;
    __syncthreads();
    if (t < 64) {
        float tot = part[0][t] + part[1][t] + part[2][t] + part[3][t];
        if (tot != 0.f) atomicAdd(&pooled[g * HDIM + t], tot);
    }
}

// ---------------- pool phase 2: mean + linear head ----------------
__global__ __launch_bounds__(640) void k_head(const float* __restrict__ pooled,
                                              const int* __restrict__ batch,
                                              const float* __restrict__ linW,
                                              const float* __restrict__ linb,
                                              float* __restrict__ out, int n) {
    int t = threadIdx.x;
    if (t >= NGRAPH * NCLS) return;
    int g = t / NCLS;
    int c = t - g * NCLS;
    int lo = 0, hi = n;
    while (lo < hi) { int m = (lo + hi) >> 1; if (batch[m] < g) lo = m + 1; else hi = m; }
    int s = lo;
    lo = 0; hi = n;
    while (lo < hi) { int m = (lo + hi) >> 1; if (batch[m] < g + 1) lo = m + 1; else hi = m; }
    float inv = 1.0f / fmaxf((float)(lo - s), 1.0f);
    float acc = linb[c];
#pragma unroll
    for (int k = 0; k < HDIM; ++k)
        acc = fmaf(pooled[g * HDIM + k] * inv, linW[k * NCLS + c], acc);
    out[g * NCLS + c] = acc;
}

extern "C" void kernel_launch(void* const* d_in, const int* in_sizes, int n_in,
                              void* d_out, int out_size, void* d_ws, size_t ws_size,
                              hipStream_t stream) {
    (void)in_sizes; (void)n_in; (void)out_size; (void)ws_size;
    const float* x    = (const float*)d_in[0];
    const int*   ei   = (const int*)d_in[1];
    const int*   batch= (const int*)d_in[2];
    const float* W1   = (const float*)d_in[3];
    const float* b1   = (const float*)d_in[4];
    const float* W2   = (const float*)d_in[5];
    const float* b2   = (const float*)d_in[6];
    const float* W3   = (const float*)d_in[7];
    const float* b3   = (const float*)d_in[8];
    const float* linW = (const float*)d_in[9];
    const float* linb = (const float*)d_in[10];
    float* out = (float*)d_out;

    const int N = N_NODES, E = N_EDGES;
    const int* src = ei;
    const int* dst = ei + E;

    char* ws = (char*)d_ws;
    float* hA     = (float*)ws; ws += (size_t)N * HDIM * 4;
    float* hB     = (float*)ws; ws += (size_t)N * HDIM * 4;   // hB = hA + N*HDIM (contiguous)
    float* dis    = (float*)ws; ws += (size_t)N * 4;
    float* selfn  = (float*)ws; ws += (size_t)N * 4;
    int2*  eadj   = (int2*)ws;  ws += (size_t)E * 8;
    int*   degi   = (int*)ws;   ws += (size_t)N * 4;
    int*   off    = (int*)ws;   ws += (size_t)N * 4;
    int*   bcur   = (int*)ws;   ws += (size_t)NBUCK * 4;
    float* pooled = (float*)ws; ws += (size_t)NGRAPH * HDIM * 4;
    int*   bsum   = (int*)ws;   ws += 256 * 4;
    int*   stage  = (int*)hA;   // aliased: consumed by k_csr before gemm1 writes hA

    const int nbN = (N + 255) / 256;   // 196
    const int nbE = (E + 255) / 256;   // 3125
    const int gb  = (N + 63) / 64;     // 782
    const int ngth = (N * 16 + 255) / 256;

    hipMemsetAsync(degi, 0, (size_t)N * 4, stream);
    hipMemsetAsync(pooled, 0, (size_t)NGRAPH * HDIM * 4, stream);
    k_deg_count<<<nbE, 256, 0, stream>>>(dst, degi, E);
    k_scan1<<<nbN, 256, 0, stream>>>(degi, off, bsum, N);
    k_scan2<<<1, 256, 0, stream>>>(bsum, nbN);
    k_scan3<<<nbN, 256, 0, stream>>>(off, bcur, bsum, degi, dis, selfn, N);
    k_part<<<(E + 4095) / 4096, 256, 0, stream>>>(src, dst, bcur, stage, E);
    k_csr<<<NBUCK, 256, 0, stream>>>(stage, off, dis, eadj, E, N);

    // layer 1: split-K x2 (y=0 -> hA, y=1 -> hB), then hA += hB
    k_gemm<F_INPUT, 2><<<dim3(gb, 2), 256, 0, stream>>>(x, W1, hA, N);
    k_sum<<<(N * HDIM / 4 + 255) / 256, 256, 0, stream>>>((float4*)hA, (const float4*)hB,
                                                          N * HDIM / 4);
    k_gather<<<ngth, 256, 0, stream>>>(hA, off, degi, eadj, selfn, b1, hB, N);
    // layer 2
    k_gemm<HDIM, 1><<<dim3(gb, 1), 256, 0, stream>>>(hB, W2, hA, N);
    k_gather<<<ngth, 256, 0, stream>>>(hA, off, degi, eadj, selfn, b2, hB, N);
    // layer 3
    k_gemm<HDIM, 1><<<dim3(gb, 1), 256, 0, stream>>>(hB, W3, hA, N);
    k_gather<<<ngth, 256, 0, stream>>>(hA, off, degi, eadj, selfn, b3, hB, N);
    // pool + head
    k_pool_acc<<<NGRAPH * 8, 256, 0, stream>>>(hB, batch, pooled, N);
    k_head<<<1, 640, 0, stream>>>(pooled, batch, linW, linb, out, N);
}

// Round 9
// 334.088 us; speedup vs baseline: 1.8954x; 1.1169x over previous
//
#include <hip/hip_runtime.h>

#define N_NODES 50000
#define N_EDGES 800000
#define F_INPUT 256
#define HDIM 64
#define NCLS 10
#define NGRAPH 64

#define BSHIFT 7                 // 128 nodes per bucket
#define NBUCK 391                // ceil(50000/128)
#define SCAP 4096                // per-bucket stage/eadj capacity (mean 2046, 45 sigma)

// ---------------- pass A: LDS-staged bucket partition ----------------
// Fixed-capacity bucket regions: no precomputed cursors needed (replaces
// deg_count + 3-phase scan). Per-block contiguous runs per bucket (~10 edges
// = 42 B) keep write amplification ~1.5x on the 3.2 MB packed payload.
__global__ __launch_bounds__(256) void k_part(const int* __restrict__ src,
                                              const int* __restrict__ dst,
                                              int* __restrict__ bcnt,
                                              int* __restrict__ stage, int E) {
    __shared__ int cnt[NBUCK];
    __shared__ int base[NBUCK];
    const int tid = threadIdx.x;
    const int e0 = blockIdx.x * 4096;
    int pb[16], pv[16];
    for (int t = tid; t < NBUCK; t += 256) cnt[t] = 0;
    __syncthreads();
#pragma unroll
    for (int j = 0; j < 16; ++j) {
        int e = e0 + j * 256 + tid;
        if (e < E) {
            int s = src[e], d = dst[e];
            pb[j] = d >> BSHIFT;
            pv[j] = (s << BSHIFT) | (d & 127);
            atomicAdd(&cnt[pb[j]], 1);
        } else pb[j] = -1;
    }
    __syncthreads();
    for (int t = tid; t < NBUCK; t += 256) {
        int c = cnt[t];
        base[t] = c ? atomicAdd(&bcnt[t], c) : 0;
        cnt[t] = 0;
    }
    __syncthreads();
#pragma unroll
    for (int j = 0; j < 16; ++j) {
        if (pb[j] >= 0) {
            int r = base[pb[j]] + atomicAdd(&cnt[pb[j]], 1);
            if (r < SCAP) stage[pb[j] * SCAP + r] = pv[j];  // 45-sigma clamp
        }
    }
}

// ---------------- pass B: per-bucket degree + scan + counting sort ----------------
// One block per bucket. LDS histogram gives per-node degree (replaces
// k_deg_count); 128-wide LDS scan gives bucket-local offsets (replaces the
// global 3-phase scan); eadj stores src only (4 B) — gather computes the
// edge weight from L2-resident dis[].
__global__ __launch_bounds__(256) void k_csr(const int* __restrict__ stage,
                                             const int* __restrict__ bcnt,
                                             int* __restrict__ degi,
                                             float* __restrict__ dis,
                                             int* __restrict__ off,
                                             int* __restrict__ eadj, int n) {
    __shared__ int cnt[128];
    __shared__ int loc[128];
    __shared__ int lcur[128];
    __shared__ int ebuf[SCAP];   // 16 KB
    const int b = blockIdx.x;
    const int tid = threadIdx.x;
    const int n0 = b << BSHIFT;
    const int nn = min(128, n - n0);
    const int sb = b * SCAP;
    const int len = min(bcnt[b], SCAP);
    if (tid < 128) cnt[tid] = 0;
    __syncthreads();
    for (int j = tid; j < len; j += 256) atomicAdd(&cnt[stage[sb + j] & 127], 1);
    __syncthreads();
    if (tid < nn) {
        int dg = cnt[tid];
        degi[n0 + tid] = dg;
        dis[n0 + tid] = rsqrtf((float)(dg + 1));
    }
    if (tid < 128) loc[tid] = cnt[tid];
    __syncthreads();
    for (int d = 1; d < 128; d <<= 1) {       // Hillis-Steele inclusive scan
        int x = 0;
        if (tid < 128 && tid >= d) x = loc[tid - d];
        __syncthreads();
        if (tid < 128) loc[tid] += x;
        __syncthreads();
    }
    if (tid < 128) {
        int ex = loc[tid] - cnt[tid];          // exclusive
        if (tid < nn) off[n0 + tid] = sb + ex;
        lcur[tid] = ex;
    }
    __syncthreads();
    for (int j = tid; j < len; j += 256) {
        int p = stage[sb + j];
        int rk = atomicAdd(&lcur[p & 127], 1);
        ebuf[rk] = p >> BSHIFT;
    }
    __syncthreads();
    for (int j = tid; j < len; j += 256) eadj[sb + j] = ebuf[j];  // linear write
}

// ---------------- fp32 GEMM: C[n,64] = A[n,FULLK] @ B[FULLK,64] ----------------
// Round-4 proven config: 64x64 tile, 256 threads, 4x4 micro-tile, VGPR 68.
// Split-K via blockIdx.y (layer 1): doubles resident waves.
template <int FULLK, int KTILES>
__global__ __launch_bounds__(256) void k_gemm(const float* __restrict__ A,
                                              const float* __restrict__ B,
                                              float* __restrict__ C, int n) {
    __shared__ float As[64][68];
    __shared__ float Bs[64][64];
    const int tid = threadIdx.x;
    const int row0 = blockIdx.x * 64;
    const int kbase = blockIdx.y * (KTILES * 64);
    const size_t coff = (size_t)blockIdx.y * N_NODES * HDIM;
    const int tx = tid & 15;
    const int ty = tid >> 4;
    const int tr = ty * 4;
    const int tc = tx * 4;
    const int lr = ty;
    const int lk = tx * 4;

    float acc[4][4];
#pragma unroll
    for (int i = 0; i < 4; ++i)
#pragma unroll
        for (int j = 0; j < 4; ++j) acc[i][j] = 0.0f;

    for (int kt = 0; kt < KTILES; ++kt) {
        const int kc = kbase + kt * 64;
#pragma unroll
        for (int j = 0; j < 4; ++j) {
            int r = lr + 16 * j;
            int grow = row0 + r;
            float4 v = make_float4(0.f, 0.f, 0.f, 0.f);
            if (grow < n) v = *(const float4*)(A + (size_t)grow * FULLK + kc + lk);
            *(float4*)&As[r][lk] = v;
        }
#pragma unroll
        for (int j = 0; j < 4; ++j) {
            int kk = lr + 16 * j;
            *(float4*)&Bs[kk][lk] = *(const float4*)(B + (size_t)(kc + kk) * HDIM + lk);
        }
        __syncthreads();
#pragma unroll
        for (int kg = 0; kg < 16; ++kg) {
            float4 b0 = *(const float4*)&Bs[kg * 4 + 0][tc];
            float4 b1 = *(const float4*)&Bs[kg * 4 + 1][tc];
            float4 b2 = *(const float4*)&Bs[kg * 4 + 2][tc];
            float4 b3 = *(const float4*)&Bs[kg * 4 + 3][tc];
#pragma unroll
            for (int i = 0; i < 4; ++i) {
                float4 av = *(const float4*)&As[tr + i][kg * 4];
                acc[i][0] = fmaf(av.x, b0.x, acc[i][0]);
                acc[i][1] = fmaf(av.x, b0.y, acc[i][1]);
                acc[i][2] = fmaf(av.x, b0.z, acc[i][2]);
                acc[i][3] = fmaf(av.x, b0.w, acc[i][3]);
                acc[i][0] = fmaf(av.y, b1.x, acc[i][0]);
                acc[i][1] = fmaf(av.y, b1.y, acc[i][1]);
                acc[i][2] = fmaf(av.y, b1.z, acc[i][2]);
                acc[i][3] = fmaf(av.y, b1.w, acc[i][3]);
                acc[i][0] = fmaf(av.z, b2.x, acc[i][0]);
                acc[i][1] = fmaf(av.z, b2.y, acc[i][1]);
                acc[i][2] = fmaf(av.z, b2.z, acc[i][2]);
                acc[i][3] = fmaf(av.z, b2.w, acc[i][3]);
                acc[i][0] = fmaf(av.w, b3.x, acc[i][0]);
                acc[i][1] = fmaf(av.w, b3.y, acc[i][1]);
                acc[i][2] = fmaf(av.w, b3.z, acc[i][2]);
                acc[i][3] = fmaf(av.w, b3.w, acc[i][3]);
            }
        }
        __syncthreads();
    }
#pragma unroll
    for (int i = 0; i < 4; ++i) {
        int grow = row0 + tr + i;
        if (grow < n) {
            *(float4*)(C + coff + (size_t)grow * HDIM + tc) =
                make_float4(acc[i][0], acc[i][1], acc[i][2], acc[i][3]);
        }
    }
}

// ---------------- split-K reduction: a += b (float4) ----------------
__global__ __launch_bounds__(256) void k_sum(float4* __restrict__ a,
                                             const float4* __restrict__ b, int n4) {
    int i = blockIdx.x * 256 + threadIdx.x;
    if (i < n4) {
        float4 x = a[i], y = b[i];
        a[i] = make_float4(x.x + y.x, x.y + y.y, x.z + y.z, x.w + y.w);
    }
}

// ---------------- pull aggregation + self-loop + bias + relu ----------------
// 16 lanes per node, each owns a float4. Edge weight computed on the fly:
// w = dis[src]*dis[i] (dis is 200 KB -> L2-resident; 16-lane broadcast).
__global__ __launch_bounds__(256) void k_gather(const float* __restrict__ h,
                                                const int* __restrict__ off,
                                                const int* __restrict__ degi,
                                                const int* __restrict__ eadj,
                                                const float* __restrict__ dis,
                                                const float* __restrict__ bias,
                                                float* __restrict__ out, int n) {
    int t = blockIdx.x * 256 + threadIdx.x;
    int i = t >> 4;
    if (i >= n) return;
    int q = (t & 15) * 4;
    float di = dis[i];
    int e0 = off[i];
    int e1 = e0 + degi[i];
    float ax = 0.f, ay = 0.f, az = 0.f, aw = 0.f;
    float bx = 0.f, by = 0.f, bz = 0.f, bw = 0.f;
    int e = e0;
    for (; e + 1 < e1; e += 2) {       // unroll x2: two row loads in flight
        int s0 = eadj[e];
        int s1 = eadj[e + 1];
        float4 v0 = *(const float4*)(h + (size_t)s0 * HDIM + q);
        float4 v1 = *(const float4*)(h + (size_t)s1 * HDIM + q);
        float w0 = dis[s0] * di;
        float w1 = dis[s1] * di;
        ax = fmaf(v0.x, w0, ax); ay = fmaf(v0.y, w0, ay);
        az = fmaf(v0.z, w0, az); aw = fmaf(v0.w, w0, aw);
        bx = fmaf(v1.x, w1, bx); by = fmaf(v1.y, w1, by);
        bz = fmaf(v1.z, w1, bz); bw = fmaf(v1.w, w1, bw);
    }
    if (e < e1) {
        int s0 = eadj[e];
        float4 v0 = *(const float4*)(h + (size_t)s0 * HDIM + q);
        float w0 = dis[s0] * di;
        ax = fmaf(v0.x, w0, ax); ay = fmaf(v0.y, w0, ay);
        az = fmaf(v0.z, w0, az); aw = fmaf(v0.w, w0, aw);
    }
    ax += bx; ay += by; az += bz; aw += bw;
    float sn = di * di;                // self-loop weight = 1/(deg+1)
    float4 hv = *(const float4*)(h + (size_t)i * HDIM + q);
    float4 b = *(const float4*)(bias + q);
    ax = fmaf(hv.x, sn, ax) + b.x;
    ay = fmaf(hv.y, sn, ay) + b.y;
    az = fmaf(hv.z, sn, az) + b.z;
    aw = fmaf(hv.w, sn, aw) + b.w;
    *(float4*)(out + (size_t)i * HDIM + q) =
        make_float4(fmaxf(ax, 0.f), fmaxf(ay, 0.f), fmaxf(az, 0.f), fmaxf(aw, 0.f));
}

// ---------------- pool phase 1: partial sums, 8 segments per graph ----------------
__global__ __launch_bounds__(256) void k_pool_acc(const float* __restrict__ h,
                                                  const int* __restrict__ batch,
                                                  float* __restrict__ pooled, int n) {
    __shared__ float part[4][64];
    int g = blockIdx.x >> 3;
    int seg = blockIdx.x & 7;
    int t = threadIdx.x;
    int f = t & 63;
    int rg = t >> 6;
    int lo = 0, hi = n;
    while (lo < hi) { int m = (lo + hi) >> 1; if (batch[m] < g) lo = m + 1; else hi = m; }
    int s = lo;
    lo = 0; hi = n;
    while (lo < hi) { int m = (lo + hi) >> 1; if (batch[m] < g + 1) lo = m + 1; else hi = m; }
    int e2 = lo;
    int len = e2 - s;
    int chunk = (len + 7) >> 3;
    int i0 = s + seg * chunk;
    int i1 = min(i0 + chunk, e2);

    float sum = 0.f;
    for (int i = i0 + rg; i < i1; i += 4) sum += h[(size_t)i * HDIM + f];
    part[rg][f] = sum;
    __syncthreads();
    if (t < 64) {
        float tot = part[0][t] + part[1][t] + part[2][t] + part[3][t];
        if (tot != 0.f) atomicAdd(&pooled[g * HDIM + t], tot);
    }
}

// ---------------- pool phase 2: mean + linear head ----------------
__global__ __launch_bounds__(640) void k_head(const float* __restrict__ pooled,
                                              const int* __restrict__ batch,
                                              const float* __restrict__ linW,
                                              const float* __restrict__ linb,
                                              float* __restrict__ out, int n) {
    int t = threadIdx.x;
    if (t >= NGRAPH * NCLS) return;
    int g = t / NCLS;
    int c = t - g * NCLS;
    int lo = 0, hi = n;
    while (lo < hi) { int m = (lo + hi) >> 1; if (batch[m] < g) lo = m + 1; else hi = m; }
    int s = lo;
    lo = 0; hi = n;
    while (lo < hi) { int m = (lo + hi) >> 1; if (batch[m] < g + 1) lo = m + 1; else hi = m; }
    float inv = 1.0f / fmaxf((float)(lo - s), 1.0f);
    float acc = linb[c];
#pragma unroll
    for (int k = 0; k < HDIM; ++k)
        acc = fmaf(pooled[g * HDIM + k] * inv, linW[k * NCLS + c], acc);
    out[g * NCLS + c] = acc;
}

extern "C" void kernel_launch(void* const* d_in, const int* in_sizes, int n_in,
                              void* d_out, int out_size, void* d_ws, size_t ws_size,
                              hipStream_t stream) {
    (void)in_sizes; (void)n_in; (void)out_size; (void)ws_size;
    const float* x    = (const float*)d_in[0];
    const int*   ei   = (const int*)d_in[1];
    const int*   batch= (const int*)d_in[2];
    const float* W1   = (const float*)d_in[3];
    const float* b1   = (const float*)d_in[4];
    const float* W2   = (const float*)d_in[5];
    const float* b2   = (const float*)d_in[6];
    const float* W3   = (const float*)d_in[7];
    const float* b3   = (const float*)d_in[8];
    const float* linW = (const float*)d_in[9];
    const float* linb = (const float*)d_in[10];
    float* out = (float*)d_out;

    const int N = N_NODES, E = N_EDGES;
    const int* src = ei;
    const int* dst = ei + E;

    char* ws = (char*)d_ws;
    float* hA     = (float*)ws; ws += (size_t)N * HDIM * 4;
    float* hB     = (float*)ws; ws += (size_t)N * HDIM * 4;   // contiguous after hA (split-K)
    float* dis    = (float*)ws; ws += (size_t)N * 4;
    int*   eadj   = (int*)ws;   ws += (size_t)NBUCK * SCAP * 4;
    int*   stage  = (int*)ws;   ws += (size_t)NBUCK * SCAP * 4;
    int*   degi   = (int*)ws;   ws += (size_t)N * 4;
    int*   off    = (int*)ws;   ws += (size_t)N * 4;
    int*   bcnt   = (int*)ws;   ws += (size_t)NBUCK * 4;
    float* pooled = (float*)ws; ws += (size_t)NGRAPH * HDIM * 4;

    const int nbE = (E + 4095) / 4096;  // 196
    const int gb  = (N + 63) / 64;      // 782
    const int ngth = (N * 16 + 255) / 256;

    hipMemsetAsync(bcnt, 0, (size_t)NBUCK * 4, stream);
    hipMemsetAsync(pooled, 0, (size_t)NGRAPH * HDIM * 4, stream);
    k_part<<<nbE, 256, 0, stream>>>(src, dst, bcnt, stage, E);
    k_csr<<<NBUCK, 256, 0, stream>>>(stage, bcnt, degi, dis, off, eadj, N);

    // layer 1: split-K x2 (y=0 -> hA, y=1 -> hB), then hA += hB
    k_gemm<F_INPUT, 2><<<dim3(gb, 2), 256, 0, stream>>>(x, W1, hA, N);
    k_sum<<<(N * HDIM / 4 + 255) / 256, 256, 0, stream>>>((float4*)hA, (const float4*)hB,
                                                          N * HDIM / 4);
    k_gather<<<ngth, 256, 0, stream>>>(hA, off, degi, eadj, dis, b1, hB, N);
    // layer 2
    k_gemm<HDIM, 1><<<dim3(gb, 1), 256, 0, stream>>>(hB, W2, hA, N);
    k_gather<<<ngth, 256, 0, stream>>>(hA, off, degi, eadj, dis, b2, hB, N);
    // layer 3
    k_gemm<HDIM, 1><<<dim3(gb, 1), 256, 0, stream>>>(hB, W3, hA, N);
    k_gather<<<ngth, 256, 0, stream>>>(hA, off, degi, eadj, dis, b3, hB, N);
    // pool + head
    k_pool_acc<<<NGRAPH * 8, 256, 0, stream>>>(hB, batch, pooled, N);
    k_head<<<1, 640, 0, stream>>>(pooled, batch, linW, linb, out, N);
}